// Round 19
// baseline (943.904 us; speedup 1.0000x reference)
//
#include <hip/hip_runtime.h>
#include <hip/hip_bf16.h>
#include <cstdint>

typedef __attribute__((ext_vector_type(8))) short u16x8;
typedef _Float16 f16_t;
typedef __attribute__((ext_vector_type(8))) f16_t f16x8;
typedef __attribute__((ext_vector_type(4))) float f32x4;

#define L_TOT 4608
#define L_TXT 512
#define L_IMG 4096
#define NH 24
#define HD 128
#define DMODEL 3072
#define NQKV 9216
#define LOG2E 1.44269504088896340736f
#define S_SHIFT 32.0f

__device__ __forceinline__ ushort f2h(float f) {
  union { f16_t h; ushort u; } c; c.h = (f16_t)f; return c.u;
}
__device__ __forceinline__ float h2f(ushort u) {
  union { ushort u; f16_t h; } c; c.u = u; return (float)c.h;
}
__device__ __forceinline__ void gload16(const ushort* g, ushort* l) {
  __builtin_amdgcn_global_load_lds((const __attribute__((address_space(1))) void*)g,
                                   (__attribute__((address_space(3))) void*)l, 16, 0, 0);
}

// ------- cvt_f32_f16: elementwise f32 -> fp16, 8 elems/thread ---------------------------
__global__ void cvt_f32_f16(const float* __restrict__ src, ushort* __restrict__ dst,
                            int n8) {
  const int i = blockIdx.x * 256 + threadIdx.x;
  if (i >= n8) return;
  const f32x4 a = *(const f32x4*)(src + (size_t)i * 8);
  const f32x4 b = *(const f32x4*)(src + (size_t)i * 8 + 4);
  alignas(16) ushort o[8];
#pragma unroll
  for (int j = 0; j < 4; ++j) { o[j] = f2h(a[j]); o[4 + j] = f2h(b[j]); }
  *(u16x8*)(dst + (size_t)i * 8) = *(const u16x8*)o;
}

// ------- tconv_w: f32 weight [3072][C], col-slice c0..c0+Nsl -> fp16 [Nsl][3072] --------
__global__ void tconv_w(const float* __restrict__ src, int C, int c0,
                        ushort* __restrict__ dst) {
  __shared__ ushort tile[64][72];
  const int nb = blockIdx.x << 6, kb = blockIdx.y << 6;
  const int t = threadIdx.x;
  const int lr = t >> 2, lc = (t & 3) << 4;
  const float* sp = src + (size_t)(kb + lr) * C + c0 + nb + lc;
  const f32x4 v0 = *(const f32x4*)sp;
  const f32x4 v1 = *(const f32x4*)(sp + 4);
  const f32x4 v2 = *(const f32x4*)(sp + 8);
  const f32x4 v3 = *(const f32x4*)(sp + 12);
#pragma unroll
  for (int i = 0; i < 4; ++i) {
    tile[lr][lc + i]      = f2h(v0[i]);
    tile[lr][lc + 4 + i]  = f2h(v1[i]);
    tile[lr][lc + 8 + i]  = f2h(v2[i]);
    tile[lr][lc + 12 + i] = f2h(v3[i]);
  }
  __syncthreads();
  const int cl = t & 63, rb = (t >> 6) << 4;
  alignas(16) ushort o[16];
#pragma unroll
  for (int i = 0; i < 16; ++i) o[i] = tile[rb + i][cl];
  ushort* dp = dst + (size_t)(nb + cl) * DMODEL + kb + rb;
  *(u16x8*)dp       = *(const u16x8*)o;
  *(u16x8*)(dp + 8) = *(const u16x8*)(o + 8);
}

// ------- tconv_h: fp16 src [R][C] -> dst [C][R] (for V -> V^T) --------------------------
__global__ void tconv_h(const ushort* __restrict__ src, ushort* __restrict__ dst,
                        int R, int C) {
  __shared__ ushort tile[64][72];
  const int r0 = blockIdx.y << 6, c0 = blockIdx.x << 6;
  const int t = threadIdx.x;
  const int lr = t >> 2, lc = (t & 3) << 4;
  const ushort* sp = src + (size_t)(r0 + lr) * C + c0 + lc;
  const u16x8 v0 = *(const u16x8*)sp;
  const u16x8 v1 = *(const u16x8*)(sp + 8);
#pragma unroll
  for (int i = 0; i < 8; ++i) {
    tile[lr][lc + i]     = ((const ushort*)&v0)[i];
    tile[lr][lc + 8 + i] = ((const ushort*)&v1)[i];
  }
  __syncthreads();
  const int cl = t & 63, rb = (t >> 6) << 4;
  alignas(16) ushort o[16];
#pragma unroll
  for (int i = 0; i < 16; ++i) o[i] = tile[rb + i][cl];
  ushort* dp = dst + (size_t)(c0 + cl) * R + r0 + rb;
  *(u16x8*)dp       = *(const u16x8*)o;
  *(u16x8*)(dp + 8) = *(const u16x8*)(o + 8);
}

// =========== gemm256: 256x256, BK=32, 8 waves, 64KB LDS -> 2 blocks/CU =================
// r14's double-buffered 2-phase schedule with the CORRECT register bound: launch_bounds
// (512,2) keeps VGPR cap 128 (kernel uses ~104, no spill); LDS 2x32KB=64KB lets the HW
// co-schedule 2 blocks/CU (2x64KB=128<=160KB) — one block's vmcnt/barrier stalls hide
// under the other's MFMA, and 324-block grids fill 512 slots instead of 2 idle rounds.
// Swizzle slot ^= (row>>1)&3 (verified conflict-free) via pre-swizzled source+ds_read.
// Per tile kt: stage kt+1 (4 loads) -> vmcnt(4) retires exactly tile kt -> barrier ->
// 12 b128 reads -> setprio(1)+32 MFMA -> end barrier (WAR for buf reuse).
// Per-block operand select: m0 < 512 -> BtLo/biasLo (enc), else BtHi/biasHi (img).
// MODE: 0 = qkv scatter ; 1 = f32 out + bias (merged proj) ; 2 = fp16 ; 3 = fp16 - SHIFT
template <int MODE>
__global__ __launch_bounds__(512, 2) void gemm256(
    const ushort* __restrict__ A, int lda,
    const ushort* __restrict__ BtLo, const ushort* __restrict__ BtHi, int ldb,
    int N, int K, void* __restrict__ out0, ushort* __restrict__ out1,
    ushort* __restrict__ out2, const float* __restrict__ biasLo,
    const float* __restrict__ biasHi, int n_base) {
  __shared__ __align__(16) ushort lds[2][2][8192];  // [buf][mat][256*32] = 64KB
  int lin = blockIdx.y * gridDim.x + blockIdx.x;
  {
    const int nwg = gridDim.x * gridDim.y;
    const int q8 = nwg >> 3, r8 = nwg & 7;
    const int xcd = lin & 7, idx = lin >> 3;
    lin = (xcd < r8 ? xcd * (q8 + 1) : r8 * (q8 + 1) + (xcd - r8) * q8) + idx;
  }
  const int m0 = (lin % gridDim.x) << 8, n0 = (lin / gridDim.x) << 8;
  const ushort* Bt = (m0 < L_TXT) ? BtLo : BtHi;
  const int tid = threadIdx.x, w = tid >> 6, lane = tid & 63;
  const int wm = w >> 2, wn = w & 3;
  const int lr = lane & 15, g4 = lane >> 4;
  // staging: lane covers row 16j + (lane>>2), phys slot lane&3; source holds logical
  // slot (lane&3) ^ ((row>>1)&3) = (lane&3) ^ ((lane>>3)&3)
  const int srow = lane >> 2;
  const int soff = 8 * ((lane & 3) ^ ((lane >> 3) & 3));  // k-elems
  f32x4 acc[8][4];
#pragma unroll
  for (int a = 0; a < 8; ++a)
#pragma unroll
    for (int b = 0; b < 4; ++b) acc[a][b] = (f32x4){0.f, 0.f, 0.f, 0.f};
  const int nt = K >> 5;

  // stage one 256x32 matrix tile of K-tile kt into buffer b: 2 gload16/thread each
  auto stageA = [&](int kt, int b) {
#pragma unroll
    for (int i = 0; i < 2; ++i) {
      const int j = w * 2 + i;
      gload16(A + (size_t)(m0 + 16 * j + srow) * lda + (kt << 5) + soff,
              &lds[b][0][j * 512]);
    }
  };
  auto stageB = [&](int kt, int b) {
#pragma unroll
    for (int i = 0; i < 2; ++i) {
      const int j = w * 2 + i;
      gload16(Bt + (size_t)(n0 + 16 * j + srow) * ldb + (kt << 5) + soff,
              &lds[b][1][j * 512]);
    }
  };
  auto readA = [&](int mi, int b) -> f16x8 {
    const int row = wm * 128 + mi * 16 + lr;
    const int byte = row * 64 + ((g4 ^ ((row >> 1) & 3)) << 4);
    return *(const f16x8*)((const char*)&lds[b][0][0] + byte);
  };
  auto readB = [&](int ni, int b) -> f16x8 {
    const int row = wn * 64 + ni * 16 + lr;
    const int byte = row * 64 + ((g4 ^ ((row >> 1) & 3)) << 4);
    return *(const f16x8*)((const char*)&lds[b][1][0] + byte);
  };

  // prologue: stage tile 0 into buf 0 (4 loads outstanding)
  stageA(0, 0); stageB(0, 0);

  for (int kt = 0; kt < nt; ++kt) {
    const int c = kt & 1, sb = c ^ 1;
    const int st = (kt + 1 < nt) ? kt + 1 : 0;  // wrap keeps ledger exact
    // issue tile kt+1 into buf sb (reads of sb finished before prev end-barrier)
    stageA(st, sb); stageB(st, sb);
    // gate: outstanding = 8 (kt, kt+1); retire exactly tile kt's 4 loads
    asm volatile("s_waitcnt vmcnt(4)" ::: "memory");
    asm volatile("s_barrier" ::: "memory");
    f16x8 bf[4], af[8];
#pragma unroll
    for (int ni = 0; ni < 4; ++ni) bf[ni] = readB(ni, c);
#pragma unroll
    for (int m = 0; m < 8; ++m) af[m] = readA(m, c);
    __builtin_amdgcn_s_setprio(1);
#pragma unroll
    for (int m = 0; m < 8; ++m)
#pragma unroll
      for (int ni = 0; ni < 4; ++ni)
        acc[m][ni] = __builtin_amdgcn_mfma_f32_16x16x32_f16(af[m], bf[ni], acc[m][ni], 0, 0, 0);
    __builtin_amdgcn_s_setprio(0);
    // end-of-tile: all reads of buf c done -> next iter may stage into it
    asm volatile("s_barrier" ::: "memory");
  }

  // ---- epilogue ----
  const int rb = (lane >> 4) << 2;
  const int cl = lane & 15;
  if (MODE == 0) {
    const int g = n_base + n0;
    const int which = g / DMODEL;
    const int col0 = g - which * DMODEL;
    ushort* dst = (which == 0) ? (ushort*)out0 : (which == 1) ? out1 : out2;
#pragma unroll
    for (int mi = 0; mi < 8; ++mi)
#pragma unroll
      for (int j = 0; j < 4; ++j) {
        const int l = m0 + wm * 128 + mi * 16 + rb + j;
        const size_t rbase = (size_t)l * DMODEL + col0 + wn * 64 + cl;
#pragma unroll
        for (int ni = 0; ni < 4; ++ni) dst[rbase + ni * 16] = f2h(acc[mi][ni][j]);
      }
  } else if (MODE == 1) {
    float* outf = (float*)out0;
    const float* bias = (m0 < L_TXT) ? biasLo : biasHi;
    const int rofs = (m0 < L_TXT) ? L_IMG : -L_TXT;  // enc rows after img block
    float bv[4];
#pragma unroll
    for (int ni = 0; ni < 4; ++ni) bv[ni] = bias[n0 + wn * 64 + ni * 16 + cl];
#pragma unroll
    for (int mi = 0; mi < 8; ++mi)
#pragma unroll
      for (int j = 0; j < 4; ++j) {
        const int r = m0 + wm * 128 + mi * 16 + rb + j + rofs;
        const size_t rbase = (size_t)r * N + n0 + wn * 64 + cl;
#pragma unroll
        for (int ni = 0; ni < 4; ++ni) outf[rbase + ni * 16] = acc[mi][ni][j] + bv[ni];
      }
  } else {
    ushort* outb = (ushort*)out0;
    const float sh = (MODE == 3) ? S_SHIFT : 0.0f;
#pragma unroll
    for (int mi = 0; mi < 8; ++mi)
#pragma unroll
      for (int j = 0; j < 4; ++j) {
        const int r = m0 + wm * 128 + mi * 16 + rb + j;
        const size_t rbase = (size_t)r * N + n0 + wn * 64 + cl;
#pragma unroll
        for (int ni = 0; ni < 4; ++ni) outb[rbase + ni * 16] = f2h(acc[mi][ni][j] - sh);
      }
  }
}

// ---------------- fused RMSNorm + RoPE on merged Q,K [l][3072] fp16; f32 params --------
__global__ void norm_rope(ushort* __restrict__ Q, ushort* __restrict__ Kg,
                          const float* __restrict__ rope,
                          const float* __restrict__ qn, const float* __restrict__ kn,
                          const float* __restrict__ eqn, const float* __restrict__ ekn) {
  const int idx = (blockIdx.x << 2) + (threadIdx.x >> 6);  // (l*24 + h)
  const int lane = threadIdx.x & 63;
  const int h = idx % NH, l = idx / NH;
  const float* qsc = (l < L_TXT) ? eqn : qn;
  const float* ksc = (l < L_TXT) ? ekn : kn;
  const size_t base = (size_t)l * DMODEL + h * HD + (lane << 1);
  const f32x4 fcv = *(const f32x4*)(rope + ((size_t)l * 64 + lane) * 4);
  const float fa = fcv[0], fb = fcv[1], fc = fcv[2], fd = fcv[3];
  const float s0 = qsc[lane << 1], s1 = qsc[(lane << 1) + 1];
  const float t0 = ksc[lane << 1], t1 = ksc[(lane << 1) + 1];
  {
    const uint32_t qv = *(const uint32_t*)&Q[base];
    float x0 = h2f((ushort)(qv & 0xffff)), x1 = h2f((ushort)(qv >> 16));
    float ss = x0 * x0 + x1 * x1;
#pragma unroll
    for (int m = 1; m < 64; m <<= 1) ss += __shfl_xor(ss, m);
    const float r = rsqrtf(ss * (1.0f / 128.0f) + 1e-6f);
    x0 *= r * s0;
    x1 *= r * s1;
    const float o0 = (fa * x0 + fb * x1) * 0.08838834764831845f;
    const float o1 = (fc * x0 + fd * x1) * 0.08838834764831845f;
    *(uint32_t*)&Q[base] = (uint32_t)f2h(o0) | ((uint32_t)f2h(o1) << 16);
  }
  {
    const uint32_t kv = *(const uint32_t*)&Kg[base];
    float x0 = h2f((ushort)(kv & 0xffff)), x1 = h2f((ushort)(kv >> 16));
    float ss = x0 * x0 + x1 * x1;
#pragma unroll
    for (int m = 1; m < 64; m <<= 1) ss += __shfl_xor(ss, m);
    const float r = rsqrtf(ss * (1.0f / 128.0f) + 1e-6f);
    x0 *= r * t0;
    x1 *= r * t1;
    const float o0 = fa * x0 + fb * x1;
    const float o1 = fc * x0 + fd * x1;
    *(uint32_t*)&Kg[base] = (uint32_t)f2h(o0) | ((uint32_t)f2h(o1) << 16);
  }
}

// ---------------- row softmax in-place on fp16 S[4608][4608] ---------------------------
__global__ void softmax_rows(ushort* __restrict__ S) {
  const int r = blockIdx.x, tid = threadIdx.x;
  ushort* Sr = S + (size_t)r * L_TOT;
  float v[18];
  float m = -3.0e38f;
#pragma unroll
  for (int j = 0; j < 18; ++j) { v[j] = h2f(Sr[tid + (j << 8)]); m = fmaxf(m, v[j]); }
#pragma unroll
  for (int o = 1; o < 64; o <<= 1) m = fmaxf(m, __shfl_xor(m, o));
  __shared__ float redm[4], reds[4];
  const int wave = tid >> 6, lane = tid & 63;
  if (lane == 0) redm[wave] = m;
  __syncthreads();
  m = fmaxf(fmaxf(redm[0], redm[1]), fmaxf(redm[2], redm[3]));
  float s = 0.f;
#pragma unroll
  for (int j = 0; j < 18; ++j) { v[j] = exp2f((v[j] - m) * LOG2E); s += v[j]; }
#pragma unroll
  for (int o = 1; o < 64; o <<= 1) s += __shfl_xor(s, o);
  if (lane == 0) reds[wave] = s;
  __syncthreads();
  const float inv = 1.0f / (reds[0] + reds[1] + reds[2] + reds[3]);
#pragma unroll
  for (int j = 0; j < 18; ++j) Sr[tid + (j << 8)] = f2h(v[j] * inv);
}

extern "C" void kernel_launch(void* const* d_in, const int* in_sizes, int n_in,
                              void* d_out, int out_size, void* d_ws, size_t ws_size,
                              hipStream_t stream) {
  (void)in_sizes; (void)n_in; (void)out_size; (void)ws_size;
  const float* hidden  = (const float*)d_in[0];
  const float* enc     = (const float*)d_in[1];
  const float* rope    = (const float*)d_in[2];
  const float* W_iqkv  = (const float*)d_in[3];
  const float* W_eqkv  = (const float*)d_in[4];
  const float* W_iproj = (const float*)d_in[5];
  const float* b_iproj = (const float*)d_in[6];
  const float* W_eproj = (const float*)d_in[7];
  const float* b_eproj = (const float*)d_in[8];
  const float* qn  = (const float*)d_in[9];
  const float* kn  = (const float*)d_in[10];
  const float* eqn = (const float*)d_in[11];
  const float* ekn = (const float*)d_in[12];
  float* out = (float*)d_out;

  // ws (ushort units), 127.4 MB proven footprint.
  // d_out (56.6 MB) holds TWO half-width W^T (enc + img) during QKV.
  // After PV, the S region (R0, 42.5 MB) holds both proj W^T (37.7 MB).
  const size_t SZ_S  = (size_t)L_TOT * L_TOT;
  const size_t SZ_LD = (size_t)L_TOT * DMODEL;
  const size_t SZ_WH = (size_t)L_TOT * DMODEL;       // half-W^T = [4608][3072]
  ushort* R0  = (ushort*)d_ws;
  ushort* CF  = R0;                       // [enc; hidden] fp16 [4608][3072]
  ushort* S   = R0;
  ushort* QR  = R0 + SZ_S;
  ushort* KR  = QR + SZ_LD;
  ushort* VR  = KR + SZ_LD;
  ushort* VT  = KR;            // alias: KR dead after S GEMM
  ushort* AO  = QR;            // alias: QR dead after S GEMM
  ushort* WTe = (ushort*)out;  // enc half-W^T in d_out
  ushort* WTi = WTe + SZ_WH;   // img half-W^T in d_out
  ushort* WPi = R0;                              // img proj W^T [3072][3072]
  ushort* WPe = R0 + (size_t)DMODEL * DMODEL;    // enc proj W^T

  dim3 blk(256);
  // inputs -> fp16, concatenated [enc; hidden]
  cvt_f32_f16<<<dim3(L_TXT * DMODEL / 8 / 256), blk, 0, stream>>>(enc, CF,
                                                                  L_TXT * DMODEL / 8);
  cvt_f32_f16<<<dim3(L_IMG * DMODEL / 8 / 256), blk, 0, stream>>>(
      hidden, CF + (size_t)L_TXT * DMODEL, L_IMG * DMODEL / 8);
  // QKV: merged enc+img, two 4608-col halves; per-block weight select (m0<512 -> enc)
  for (int h = 0; h < 2; ++h) {
    const int c0 = h * 4608;
    tconv_w<<<dim3(72, 48), blk, 0, stream>>>(W_eqkv, NQKV, c0, WTe);
    tconv_w<<<dim3(72, 48), blk, 0, stream>>>(W_iqkv, NQKV, c0, WTi);
    gemm256<0><<<dim3(L_TOT / 256, 18), dim3(512), 0, stream>>>(
        CF, DMODEL, WTe, WTi, DMODEL, 4608, DMODEL,
        QR, KR, VR, nullptr, nullptr, c0);
  }
  // per-head RMSNorm + RoPE (attn scale folded into Q)
  norm_rope<<<dim3(L_TOT * NH / 4), blk, 0, stream>>>(QR, KR, rope, qn, kn, eqn, ekn);
  // S = Q K^T - 32 (fp16)
  gemm256<3><<<dim3(L_TOT / 256, L_TOT / 256), dim3(512), 0, stream>>>(
      QR, DMODEL, KR, KR, DMODEL, L_TOT, DMODEL, S, nullptr, nullptr,
      nullptr, nullptr, 0);
  // row softmax in place
  softmax_rows<<<dim3(L_TOT), blk, 0, stream>>>(S);
  // V^T (fp16 [3072][4608]) for the PV GEMM
  tconv_h<<<dim3(48, 72), blk, 0, stream>>>(VR, VT, L_TOT, DMODEL);
  // AO = P @ V
  gemm256<2><<<dim3(L_TOT / 256, DMODEL / 256), dim3(512), 0, stream>>>(
      S, L_TOT, VT, VT, L_TOT, DMODEL, L_TOT, AO, nullptr, nullptr,
      nullptr, nullptr, 0);
  // output projections: merged enc+img, per-block weight/bias select + row remap
  tconv_w<<<dim3(48, 48), blk, 0, stream>>>(W_iproj, DMODEL, 0, WPi);
  tconv_w<<<dim3(48, 48), blk, 0, stream>>>(W_eproj, DMODEL, 0, WPe);
  gemm256<1><<<dim3(L_TOT / 256, DMODEL / 256), dim3(512), 0, stream>>>(
      AO, DMODEL, WPe, WPi, DMODEL, DMODEL, DMODEL,
      out, nullptr, nullptr, b_eproj, b_iproj, 0);
}

// Round 20
// 820.164 us; speedup vs baseline: 1.1509x; 1.1509x over previous
//
#include <hip/hip_runtime.h>
#include <hip/hip_bf16.h>
#include <cstdint>

typedef __attribute__((ext_vector_type(8))) short u16x8;
typedef _Float16 f16_t;
typedef __attribute__((ext_vector_type(8))) f16_t f16x8;
typedef __attribute__((ext_vector_type(4))) float f32x4;

#define L_TOT 4608
#define L_TXT 512
#define L_IMG 4096
#define NH 24
#define HD 128
#define DMODEL 3072
#define NQKV 9216
#define LOG2E 1.44269504088896340736f
#define S_SHIFT 32.0f

__device__ __forceinline__ ushort f2h(float f) {
  union { f16_t h; ushort u; } c; c.h = (f16_t)f; return c.u;
}
__device__ __forceinline__ float h2f(ushort u) {
  union { ushort u; f16_t h; } c; c.u = u; return (float)c.h;
}
__device__ __forceinline__ void gload16(const ushort* g, ushort* l) {
  __builtin_amdgcn_global_load_lds((const __attribute__((address_space(1))) void*)g,
                                   (__attribute__((address_space(3))) void*)l, 16, 0, 0);
}

// ------- cvt_f32_f16: elementwise f32 -> fp16, 8 elems/thread ---------------------------
__global__ void cvt_f32_f16(const float* __restrict__ src, ushort* __restrict__ dst,
                            int n8) {
  const int i = blockIdx.x * 256 + threadIdx.x;
  if (i >= n8) return;
  const f32x4 a = *(const f32x4*)(src + (size_t)i * 8);
  const f32x4 b = *(const f32x4*)(src + (size_t)i * 8 + 4);
  alignas(16) ushort o[8];
#pragma unroll
  for (int j = 0; j < 4; ++j) { o[j] = f2h(a[j]); o[4 + j] = f2h(b[j]); }
  *(u16x8*)(dst + (size_t)i * 8) = *(const u16x8*)o;
}

// ------- tconv_w: f32 weight [3072][C], col-slice c0..c0+Nsl -> fp16 [Nsl][3072] --------
__global__ void tconv_w(const float* __restrict__ src, int C, int c0,
                        ushort* __restrict__ dst) {
  __shared__ ushort tile[64][72];
  const int nb = blockIdx.x << 6, kb = blockIdx.y << 6;
  const int t = threadIdx.x;
  const int lr = t >> 2, lc = (t & 3) << 4;
  const float* sp = src + (size_t)(kb + lr) * C + c0 + nb + lc;
  const f32x4 v0 = *(const f32x4*)sp;
  const f32x4 v1 = *(const f32x4*)(sp + 4);
  const f32x4 v2 = *(const f32x4*)(sp + 8);
  const f32x4 v3 = *(const f32x4*)(sp + 12);
#pragma unroll
  for (int i = 0; i < 4; ++i) {
    tile[lr][lc + i]      = f2h(v0[i]);
    tile[lr][lc + 4 + i]  = f2h(v1[i]);
    tile[lr][lc + 8 + i]  = f2h(v2[i]);
    tile[lr][lc + 12 + i] = f2h(v3[i]);
  }
  __syncthreads();
  const int cl = t & 63, rb = (t >> 6) << 4;
  alignas(16) ushort o[16];
#pragma unroll
  for (int i = 0; i < 16; ++i) o[i] = tile[rb + i][cl];
  ushort* dp = dst + (size_t)(nb + cl) * DMODEL + kb + rb;
  *(u16x8*)dp       = *(const u16x8*)o;
  *(u16x8*)(dp + 8) = *(const u16x8*)(o + 8);
}

// ------- tconv_h: fp16 src [R][C] -> dst [C][R] (for V -> V^T) --------------------------
__global__ void tconv_h(const ushort* __restrict__ src, ushort* __restrict__ dst,
                        int R, int C) {
  __shared__ ushort tile[64][72];
  const int r0 = blockIdx.y << 6, c0 = blockIdx.x << 6;
  const int t = threadIdx.x;
  const int lr = t >> 2, lc = (t & 3) << 4;
  const ushort* sp = src + (size_t)(r0 + lr) * C + c0 + lc;
  const u16x8 v0 = *(const u16x8*)sp;
  const u16x8 v1 = *(const u16x8*)(sp + 8);
#pragma unroll
  for (int i = 0; i < 8; ++i) {
    tile[lr][lc + i]     = ((const ushort*)&v0)[i];
    tile[lr][lc + 8 + i] = ((const ushort*)&v1)[i];
  }
  __syncthreads();
  const int cl = t & 63, rb = (t >> 6) << 4;
  alignas(16) ushort o[16];
#pragma unroll
  for (int i = 0; i < 16; ++i) o[i] = tile[rb + i][cl];
  ushort* dp = dst + (size_t)(c0 + cl) * R + r0 + rb;
  *(u16x8*)dp       = *(const u16x8*)o;
  *(u16x8*)(dp + 8) = *(const u16x8*)(o + 8);
}

// =========== gemm256: 256x256, BK=64, 8 waves, 2-phase counted schedule ================
// Body identical to round-18 best. Per-block operand select for merged enc+img
// dispatches: m0 < 512 -> BtLo/biasLo (enc), else BtHi/biasHi (img). MODE 1 remaps
// output rows (enc rows -> out + L_IMG).
// MODE: 0 = qkv scatter ; 1 = f32 out + bias (merged proj) ; 2 = fp16 ; 3 = fp16 - SHIFT
template <int MODE>
__global__ __launch_bounds__(512, 2) void gemm256(
    const ushort* __restrict__ A, int lda,
    const ushort* __restrict__ BtLo, const ushort* __restrict__ BtHi, int ldb,
    int N, int K, void* __restrict__ out0, ushort* __restrict__ out1,
    ushort* __restrict__ out2, const float* __restrict__ biasLo,
    const float* __restrict__ biasHi, int n_base) {
  __shared__ __align__(16) ushort lds[2][2][2][8192];  // [buf][khalf][mat][256*32]
  int lin = blockIdx.y * gridDim.x + blockIdx.x;
  {
    const int nwg = gridDim.x * gridDim.y;
    const int q8 = nwg >> 3, r8 = nwg & 7;
    const int xcd = lin & 7, idx = lin >> 3;
    lin = (xcd < r8 ? xcd * (q8 + 1) : r8 * (q8 + 1) + (xcd - r8) * q8) + idx;
  }
  const int m0 = (lin % gridDim.x) << 8, n0 = (lin / gridDim.x) << 8;
  const ushort* Bt = (m0 < L_TXT) ? BtLo : BtHi;
  const int tid = threadIdx.x, w = tid >> 6, lane = tid & 63;
  const int wm = w >> 2, wn = w & 3;
  const int lr = lane & 15, g4 = lane >> 4;
  const int srow = lane >> 2;
  const int soff = 8 * ((lane & 3) ^ ((lane >> 3) & 3));  // k-elems within half
  f32x4 acc[8][4];
#pragma unroll
  for (int a = 0; a < 8; ++a)
#pragma unroll
    for (int b = 0; b < 4; ++b) acc[a][b] = (f32x4){0.f, 0.f, 0.f, 0.f};
  const int nt = K >> 6;

  auto stageA = [&](int h, int kt, int b) {
#pragma unroll
    for (int i = 0; i < 2; ++i) {
      const int j = w * 2 + i;
      gload16(A + (size_t)(m0 + 16 * j + srow) * lda + (kt << 6) + 32 * h + soff,
              &lds[b][h][0][j * 512]);
    }
  };
  auto stageB = [&](int h, int kt, int b) {
#pragma unroll
    for (int i = 0; i < 2; ++i) {
      const int j = w * 2 + i;
      gload16(Bt + (size_t)(n0 + 16 * j + srow) * ldb + (kt << 6) + 32 * h + soff,
              &lds[b][h][1][j * 512]);
    }
  };
  auto readA = [&](int h, int mi, int b) -> f16x8 {
    const int row = wm * 128 + mi * 16 + lr;
    const int byte = row * 64 + ((g4 ^ ((row >> 1) & 3)) << 4);
    return *(const f16x8*)((const char*)&lds[b][h][0][0] + byte);
  };
  auto readB = [&](int h, int ni, int b) -> f16x8 {
    const int row = wn * 64 + ni * 16 + lr;
    const int byte = row * 64 + ((g4 ^ ((row >> 1) & 3)) << 4);
    return *(const f16x8*)((const char*)&lds[b][h][1][0] + byte);
  };

  // prologue: stage tile 0 in consumption order (8 loads outstanding)
  stageA(0, 0, 0); stageB(0, 0, 0); stageA(1, 0, 0); stageB(1, 0, 0);

  for (int kt = 0; kt < nt; ++kt) {
    const int c = kt & 1, sb = c ^ 1;
    const int st = (kt + 1 < nt) ? kt + 1 : 0;  // wrap keeps ledger exact
    f16x8 bf[4], af[8];
    // ==== phase 0: k-lo ====
    asm volatile("s_waitcnt vmcnt(4)" ::: "memory");
    asm volatile("s_barrier" ::: "memory");
    stageA(0, st, sb); stageB(0, st, sb);
#pragma unroll
    for (int ni = 0; ni < 4; ++ni) bf[ni] = readB(0, ni, c);
#pragma unroll
    for (int m = 0; m < 8; ++m) af[m] = readA(0, m, c);
    __builtin_amdgcn_s_setprio(1);
#pragma unroll
    for (int m = 0; m < 8; ++m)
#pragma unroll
      for (int ni = 0; ni < 4; ++ni)
        acc[m][ni] = __builtin_amdgcn_mfma_f32_16x16x32_f16(af[m], bf[ni], acc[m][ni], 0, 0, 0);
    __builtin_amdgcn_s_setprio(0);
    // ==== phase 1: k-hi ====
    asm volatile("s_waitcnt vmcnt(4)" ::: "memory");
    asm volatile("s_barrier" ::: "memory");
    stageA(1, st, sb); stageB(1, st, sb);
#pragma unroll
    for (int ni = 0; ni < 4; ++ni) bf[ni] = readB(1, ni, c);
#pragma unroll
    for (int m = 0; m < 8; ++m) af[m] = readA(1, m, c);
    __builtin_amdgcn_s_setprio(1);
#pragma unroll
    for (int m = 0; m < 8; ++m)
#pragma unroll
      for (int ni = 0; ni < 4; ++ni)
        acc[m][ni] = __builtin_amdgcn_mfma_f32_16x16x32_f16(af[m], bf[ni], acc[m][ni], 0, 0, 0);
    __builtin_amdgcn_s_setprio(0);
  }

  // ---- epilogue ----
  const int rb = (lane >> 4) << 2;
  const int cl = lane & 15;
  if (MODE == 0) {
    const int g = n_base + n0;
    const int which = g / DMODEL;
    const int col0 = g - which * DMODEL;
    ushort* dst = (which == 0) ? (ushort*)out0 : (which == 1) ? out1 : out2;
#pragma unroll
    for (int mi = 0; mi < 8; ++mi)
#pragma unroll
      for (int j = 0; j < 4; ++j) {
        const int l = m0 + wm * 128 + mi * 16 + rb + j;
        const size_t rbase = (size_t)l * DMODEL + col0 + wn * 64 + cl;
#pragma unroll
        for (int ni = 0; ni < 4; ++ni) dst[rbase + ni * 16] = f2h(acc[mi][ni][j]);
      }
  } else if (MODE == 1) {
    float* outf = (float*)out0;
    const float* bias = (m0 < L_TXT) ? biasLo : biasHi;
    const int rofs = (m0 < L_TXT) ? L_IMG : -L_TXT;  // enc rows after img block
    float bv[4];
#pragma unroll
    for (int ni = 0; ni < 4; ++ni) bv[ni] = bias[n0 + wn * 64 + ni * 16 + cl];
#pragma unroll
    for (int mi = 0; mi < 8; ++mi)
#pragma unroll
      for (int j = 0; j < 4; ++j) {
        const int r = m0 + wm * 128 + mi * 16 + rb + j + rofs;
        const size_t rbase = (size_t)r * N + n0 + wn * 64 + cl;
#pragma unroll
        for (int ni = 0; ni < 4; ++ni) outf[rbase + ni * 16] = acc[mi][ni][j] + bv[ni];
      }
  } else {
    ushort* outb = (ushort*)out0;
    const float sh = (MODE == 3) ? S_SHIFT : 0.0f;
#pragma unroll
    for (int mi = 0; mi < 8; ++mi)
#pragma unroll
      for (int j = 0; j < 4; ++j) {
        const int r = m0 + wm * 128 + mi * 16 + rb + j;
        const size_t rbase = (size_t)r * N + n0 + wn * 64 + cl;
#pragma unroll
        for (int ni = 0; ni < 4; ++ni) outb[rbase + ni * 16] = f2h(acc[mi][ni][j] - sh);
      }
  }
}

// ---------------- fused RMSNorm + RoPE on merged Q,K [l][3072] fp16; f32 params --------
__global__ void norm_rope(ushort* __restrict__ Q, ushort* __restrict__ Kg,
                          const float* __restrict__ rope,
                          const float* __restrict__ qn, const float* __restrict__ kn,
                          const float* __restrict__ eqn, const float* __restrict__ ekn) {
  const int idx = (blockIdx.x << 2) + (threadIdx.x >> 6);  // (l*24 + h)
  const int lane = threadIdx.x & 63;
  const int h = idx % NH, l = idx / NH;
  const float* qsc = (l < L_TXT) ? eqn : qn;
  const float* ksc = (l < L_TXT) ? ekn : kn;
  const size_t base = (size_t)l * DMODEL + h * HD + (lane << 1);
  const f32x4 fcv = *(const f32x4*)(rope + ((size_t)l * 64 + lane) * 4);
  const float fa = fcv[0], fb = fcv[1], fc = fcv[2], fd = fcv[3];
  const float s0 = qsc[lane << 1], s1 = qsc[(lane << 1) + 1];
  const float t0 = ksc[lane << 1], t1 = ksc[(lane << 1) + 1];
  {
    const uint32_t qv = *(const uint32_t*)&Q[base];
    float x0 = h2f((ushort)(qv & 0xffff)), x1 = h2f((ushort)(qv >> 16));
    float ss = x0 * x0 + x1 * x1;
#pragma unroll
    for (int m = 1; m < 64; m <<= 1) ss += __shfl_xor(ss, m);
    const float r = rsqrtf(ss * (1.0f / 128.0f) + 1e-6f);
    x0 *= r * s0;
    x1 *= r * s1;
    const float o0 = (fa * x0 + fb * x1) * 0.08838834764831845f;
    const float o1 = (fc * x0 + fd * x1) * 0.08838834764831845f;
    *(uint32_t*)&Q[base] = (uint32_t)f2h(o0) | ((uint32_t)f2h(o1) << 16);
  }
  {
    const uint32_t kv = *(const uint32_t*)&Kg[base];
    float x0 = h2f((ushort)(kv & 0xffff)), x1 = h2f((ushort)(kv >> 16));
    float ss = x0 * x0 + x1 * x1;
#pragma unroll
    for (int m = 1; m < 64; m <<= 1) ss += __shfl_xor(ss, m);
    const float r = rsqrtf(ss * (1.0f / 128.0f) + 1e-6f);
    x0 *= r * t0;
    x1 *= r * t1;
    const float o0 = fa * x0 + fb * x1;
    const float o1 = fc * x0 + fd * x1;
    *(uint32_t*)&Kg[base] = (uint32_t)f2h(o0) | ((uint32_t)f2h(o1) << 16);
  }
}

// ---------------- row softmax in-place on fp16 S[4608][4608] ---------------------------
__global__ void softmax_rows(ushort* __restrict__ S) {
  const int r = blockIdx.x, tid = threadIdx.x;
  ushort* Sr = S + (size_t)r * L_TOT;
  float v[18];
  float m = -3.0e38f;
#pragma unroll
  for (int j = 0; j < 18; ++j) { v[j] = h2f(Sr[tid + (j << 8)]); m = fmaxf(m, v[j]); }
#pragma unroll
  for (int o = 1; o < 64; o <<= 1) m = fmaxf(m, __shfl_xor(m, o));
  __shared__ float redm[4], reds[4];
  const int wave = tid >> 6, lane = tid & 63;
  if (lane == 0) redm[wave] = m;
  __syncthreads();
  m = fmaxf(fmaxf(redm[0], redm[1]), fmaxf(redm[2], redm[3]));
  float s = 0.f;
#pragma unroll
  for (int j = 0; j < 18; ++j) { v[j] = exp2f((v[j] - m) * LOG2E); s += v[j]; }
#pragma unroll
  for (int o = 1; o < 64; o <<= 1) s += __shfl_xor(s, o);
  if (lane == 0) reds[wave] = s;
  __syncthreads();
  const float inv = 1.0f / (reds[0] + reds[1] + reds[2] + reds[3]);
#pragma unroll
  for (int j = 0; j < 18; ++j) Sr[tid + (j << 8)] = f2h(v[j] * inv);
}

extern "C" void kernel_launch(void* const* d_in, const int* in_sizes, int n_in,
                              void* d_out, int out_size, void* d_ws, size_t ws_size,
                              hipStream_t stream) {
  (void)in_sizes; (void)n_in; (void)out_size;
  const float* hidden  = (const float*)d_in[0];
  const float* enc     = (const float*)d_in[1];
  const float* rope    = (const float*)d_in[2];
  const float* W_iqkv  = (const float*)d_in[3];
  const float* W_eqkv  = (const float*)d_in[4];
  const float* W_iproj = (const float*)d_in[5];
  const float* b_iproj = (const float*)d_in[6];
  const float* W_eproj = (const float*)d_in[7];
  const float* b_eproj = (const float*)d_in[8];
  const float* qn  = (const float*)d_in[9];
  const float* kn  = (const float*)d_in[10];
  const float* eqn = (const float*)d_in[11];
  const float* ekn = (const float*)d_in[12];
  float* out = (float*)d_out;

  // ws layout (ushort units). Proven base footprint 127.4 MB:
  //   R0 = S region (42.5 MB): CF during QKV -> S -> proj W^T pair
  //   QR (->AO), KR (->VT), VR
  // If ws_size >= 241 MB, two FULL W^T (113 MB) live past the base footprint and
  // QKV runs as ONE 648-block dispatch (84% fill vs 63%); else r18 half-loop.
  const size_t SZ_S  = (size_t)L_TOT * L_TOT;
  const size_t SZ_LD = (size_t)L_TOT * DMODEL;
  const size_t SZ_WH = (size_t)L_TOT * DMODEL;       // half-W^T = [4608][3072]
  const size_t SZ_W  = (size_t)NQKV * DMODEL;        // full W^T = [9216][3072]
  ushort* R0  = (ushort*)d_ws;
  ushort* CF  = R0;                       // [enc; hidden] fp16 [4608][3072]
  ushort* S   = R0;
  ushort* QR  = R0 + SZ_S;
  ushort* KR  = QR + SZ_LD;
  ushort* VR  = KR + SZ_LD;
  ushort* VT  = KR;            // alias: KR dead after S GEMM
  ushort* AO  = QR;            // alias: QR dead after S GEMM
  ushort* WTe = (ushort*)out;  // enc half-W^T in d_out (fallback path)
  ushort* WTi = WTe + SZ_WH;   // img half-W^T in d_out (fallback path)
  ushort* WQe = VR + SZ_LD;    // full enc W^T (big-ws path)
  ushort* WQi = WQe + SZ_W;    // full img W^T (big-ws path)
  ushort* WPi = R0;                              // img proj W^T [3072][3072]
  ushort* WPe = R0 + (size_t)DMODEL * DMODEL;    // enc proj W^T
  const bool big = ws_size >= (SZ_S + 3 * SZ_LD + 2 * SZ_W) * sizeof(ushort);

  dim3 blk(256);
  // inputs -> fp16, concatenated [enc; hidden]
  cvt_f32_f16<<<dim3(L_TXT * DMODEL / 8 / 256), blk, 0, stream>>>(enc, CF,
                                                                  L_TXT * DMODEL / 8);
  cvt_f32_f16<<<dim3(L_IMG * DMODEL / 8 / 256), blk, 0, stream>>>(
      hidden, CF + (size_t)L_TXT * DMODEL, L_IMG * DMODEL / 8);
  if (big) {
    // QKV: single merged dispatch, full N=9216 (648 blocks, 84% fill)
    tconv_w<<<dim3(NQKV / 64, DMODEL / 64), blk, 0, stream>>>(W_eqkv, NQKV, 0, WQe);
    tconv_w<<<dim3(NQKV / 64, DMODEL / 64), blk, 0, stream>>>(W_iqkv, NQKV, 0, WQi);
    gemm256<0><<<dim3(L_TOT / 256, NQKV / 256), dim3(512), 0, stream>>>(
        CF, DMODEL, WQe, WQi, DMODEL, NQKV, DMODEL,
        QR, KR, VR, nullptr, nullptr, 0);
  } else {
    // fallback: two 4608-col halves through d_out scratch (r18 path)
    for (int h = 0; h < 2; ++h) {
      const int c0 = h * 4608;
      tconv_w<<<dim3(72, 48), blk, 0, stream>>>(W_eqkv, NQKV, c0, WTe);
      tconv_w<<<dim3(72, 48), blk, 0, stream>>>(W_iqkv, NQKV, c0, WTi);
      gemm256<0><<<dim3(L_TOT / 256, 18), dim3(512), 0, stream>>>(
          CF, DMODEL, WTe, WTi, DMODEL, 4608, DMODEL,
          QR, KR, VR, nullptr, nullptr, c0);
    }
  }
  // per-head RMSNorm + RoPE (attn scale folded into Q)
  norm_rope<<<dim3(L_TOT * NH / 4), blk, 0, stream>>>(QR, KR, rope, qn, kn, eqn, ekn);
  // S = Q K^T - 32 (fp16)
  gemm256<3><<<dim3(L_TOT / 256, L_TOT / 256), dim3(512), 0, stream>>>(
      QR, DMODEL, KR, KR, DMODEL, L_TOT, DMODEL, S, nullptr, nullptr,
      nullptr, nullptr, 0);
  // row softmax in place
  softmax_rows<<<dim3(L_TOT), blk, 0, stream>>>(S);
  // V^T (fp16 [3072][4608]) for the PV GEMM
  tconv_h<<<dim3(48, 72), blk, 0, stream>>>(VR, VT, L_TOT, DMODEL);
  // AO = P @ V
  gemm256<2><<<dim3(L_TOT / 256, DMODEL / 256), dim3(512), 0, stream>>>(
      S, L_TOT, VT, VT, L_TOT, DMODEL, L_TOT, AO, nullptr, nullptr,
      nullptr, nullptr, 0);
  // output projections: merged enc+img, per-block weight/bias select + row remap
  tconv_w<<<dim3(48, 48), blk, 0, stream>>>(W_iproj, DMODEL, 0, WPi);
  tconv_w<<<dim3(48, 48), blk, 0, stream>>>(W_eproj, DMODEL, 0, WPe);
  gemm256<1><<<dim3(L_TOT / 256, DMODEL / 256), dim3(512), 0, stream>>>(
      AO, DMODEL, WPe, WPi, DMODEL, DMODEL, DMODEL,
      out, nullptr, nullptr, b_eproj, b_iproj, 0);
}